// Round 9
// baseline (816.218 us; speedup 1.0000x reference)
//
#include <hip/hip_runtime.h>
#include <cstddef>
#include <cstdint>

constexpr int kN    = 1024;
constexpr int kE    = 8192;
constexpr int kQL   = 8;
constexpr int kHID  = 1024;

typedef __bf16 bf16x8 __attribute__((ext_vector_type(8)));
typedef float  f32x4  __attribute__((ext_vector_type(4)));
typedef unsigned short ushort8 __attribute__((ext_vector_type(8)));

__device__ __forceinline__ unsigned short f2bf(float f) {
  unsigned u = __float_as_uint(f);
  unsigned r = (u + 0x7FFFu + ((u >> 16) & 1u)) >> 16;
  return (unsigned short)r;
}
__device__ __forceinline__ float bf2f(unsigned short u) {
  return __uint_as_float((unsigned)u << 16);
}
__device__ __forceinline__ unsigned pkbf(float a, float b) {
  return (unsigned)f2bf(a) | ((unsigned)f2bf(b) << 16);
}
__device__ __forceinline__ void gload_lds16(const void* g, void* l) {
  __builtin_amdgcn_global_load_lds(
      (const __attribute__((address_space(1))) void*)g,
      (__attribute__((address_space(3))) void*)l, 16, 0, 0);
}

// ---------- RoPE tables: ct/st[p][j], p<16, j<32 ----------
__global__ void rope_tables_kernel(float* __restrict__ ct, float* __restrict__ st) {
  int i = threadIdx.x;              // 512 threads
  int p = i >> 5, j = i & 31;
  float inv = expf(-((float)(2 * j) / 64.0f) * logf(10000.0f));
  float ang = (float)p * inv;
  ct[i] = cosf(ang);
  st[i] = sinf(ang);
}

// ---------- fp32 -> bf16 convert (8 elems/thread) ----------
__global__ __launch_bounds__(256) void cvt_kernel(
    const float* __restrict__ in, unsigned short* __restrict__ out, int n8) {
  int i = blockIdx.x * 256 + threadIdx.x;
  if (i >= n8) return;
  const float4* p = (const float4*)(in + (size_t)i * 8);
  float4 a = p[0], b = p[1];
  uint4 o;
  o.x = f2bf(a.x) | ((unsigned)f2bf(a.y) << 16);
  o.y = f2bf(a.z) | ((unsigned)f2bf(a.w) << 16);
  o.z = f2bf(b.x) | ((unsigned)f2bf(b.y) << 16);
  o.w = f2bf(b.z) | ((unsigned)f2bf(b.w) << 16);
  *(uint4*)(out + (size_t)i * 8) = o;
}

// ---------- gate/up weights -> 16-col interleaved fused layout ----------
__global__ __launch_bounds__(256) void cvt_gu_kernel(
    const float* __restrict__ Wg, const float* __restrict__ Wu,
    unsigned short* __restrict__ out) {
  int i = blockIdx.x * 256 + threadIdx.x;   // 8192*128
  int n = i >> 7, ck = (i & 127) * 8;
  int isUp = (n >> 4) & 1;
  int srow = (n >> 6) * 32 + ((n >> 5) & 1) * 16 + (n & 15);
  const float* src = (isUp ? Wu : Wg) + (size_t)srow * 1024 + ck;
  const float4* p = (const float4*)src;
  float4 a = p[0], b = p[1];
  uint4 o;
  o.x = f2bf(a.x) | ((unsigned)f2bf(a.y) << 16);
  o.y = f2bf(a.z) | ((unsigned)f2bf(a.w) << 16);
  o.z = f2bf(b.x) | ((unsigned)f2bf(b.y) << 16);
  o.w = f2bf(b.z) | ((unsigned)f2bf(b.w) << 16);
  *(uint4*)(out + (size_t)n * 1024 + ck) = o;
}

// ---------- RMSNorm: fp32 in -> bf16 out, one block per row ----------
__global__ __launch_bounds__(256) void rmsnorm_bf16_kernel(
    const float* __restrict__ in, const float* __restrict__ w,
    unsigned short* __restrict__ out) {
  __shared__ float red[4];
  int row = blockIdx.x, tid = threadIdx.x;
  const float* p = in + (size_t)row * kHID + tid * 4;
  float4 v = *(const float4*)p;
  float ss = v.x*v.x + v.y*v.y + v.z*v.z + v.w*v.w;
  #pragma unroll
  for (int off = 32; off > 0; off >>= 1) ss += __shfl_down(ss, off);
  int lane = tid & 63, wv = tid >> 6;
  if (lane == 0) red[wv] = ss;
  __syncthreads();
  float tot = red[0] + red[1] + red[2] + red[3];
  float rn = rsqrtf(tot * (1.0f / (float)kHID) + 1e-6f);
  float4 w4 = *(const float4*)(w + tid * 4);
  uint2 o;
  o.x = f2bf(v.x*rn*w4.x) | ((unsigned)f2bf(v.y*rn*w4.y) << 16);
  o.y = f2bf(v.z*rn*w4.z) | ((unsigned)f2bf(v.w*rn*w4.w) << 16);
  *(uint2*)(out + (size_t)row * kHID + tid * 4) = o;
}

// ---------- 128x128 m97-structure bf16 MFMA GEMM ----------
// C[M,N] = A[M,K]*B[N,K]^T. 256 thr = 4 waves (2M x 2N, 64x64 each), BK=32,
// SINGLE-buffer LDS (16 KiB), plain __syncthreads (compiler-managed waits),
// gload_lds w16, chunk-XOR swizzle f(row)=(row>>1)&3 (R5/R8-verified 0-conflict)
// on stage-source + read. No inline asm / setprio / sched_barrier: the
// validated m97 recipe relies on 3-4 blocks/CU cross-block overlap.
// OUTMODE: 0=f32(+resid)  2=silu(gate)*up pairs->bf16 (N_out=N/2)
//          4=bf16 + q-rope cols [0,1024), k-rope [1024,1536) pos even
template<int OUTMODE>
__global__ __launch_bounds__(256) void gemm97(
    const unsigned short* __restrict__ A, const unsigned short* __restrict__ B,
    const float* __restrict__ resid, void* __restrict__ Cout,
    const float* __restrict__ ct, const float* __restrict__ st,
    int M, int N, int K) {
  __shared__ unsigned short As[4096];   // [128][32]
  __shared__ unsigned short Bs[4096];
  const int tid = threadIdx.x;
  const int lane = tid & 63, wid = tid >> 6;
  const int gx = gridDim.x;
  int id = blockIdx.y * gx + blockIdx.x;
  {
    const int nwg = gx * gridDim.y;     // all grids %8 == 0
    const int cpx = nwg >> 3;
    id = (id & 7) * cpx + (id >> 3);    // XCD-chunked: consecutive logical
  }                                     // tiles (sharing A panel) co-XCD
  const int m0 = (id / gx) * 128, n0 = (id % gx) * 128;
  const int wr = wid >> 1, wc = wid & 1;
  const int l15 = lane & 15, lg = lane >> 4;
  const int NT = K >> 5;

  // staging: thread t -> rows (t>>2) and +64, source chunk pre-XOR'd so
  // LDS[row][c] = global[row][c ^ ((row>>1)&3)]; (row+64) keeps same XOR.
  const int sr = tid >> 2, sc = tid & 3;
  const unsigned short* Asrc = A + (size_t)(m0 + sr) * K + (sc ^ ((sr >> 1) & 3)) * 8;
  const unsigned short* Bsrc = B + (size_t)(n0 + sr) * K + (sc ^ ((sr >> 1) & 3)) * 8;
  const size_t rK64 = (size_t)64 * K;
  const int rck = (lg ^ ((l15 >> 1) & 3)) * 8;   // read-side swizzle

  f32x4 acc[4][4] = {};
  for (int t = 0; t < NT; ++t) {
    __syncthreads();                    // all waves done reading LDS
    const size_t k0 = (size_t)t * 32;
    gload_lds16(Asrc + k0,        As + wid * 512);
    gload_lds16(Asrc + rK64 + k0, As + 2048 + wid * 512);
    gload_lds16(Bsrc + k0,        Bs + wid * 512);
    gload_lds16(Bsrc + rK64 + k0, Bs + 2048 + wid * 512);
    __syncthreads();                    // compiler drains vmcnt before barrier
    bf16x8 af[4], bf[4];
    #pragma unroll
    for (int mi = 0; mi < 4; ++mi)
      af[mi] = *(const bf16x8*)&As[(wr * 64 + mi * 16 + l15) * 32 + rck];
    #pragma unroll
    for (int nj = 0; nj < 4; ++nj)
      bf[nj] = *(const bf16x8*)&Bs[(wc * 64 + nj * 16 + l15) * 32 + rck];
    #pragma unroll
    for (int mi = 0; mi < 4; ++mi)
      #pragma unroll
      for (int nj = 0; nj < 4; ++nj)
        acc[mi][nj] = __builtin_amdgcn_mfma_f32_16x16x32_bf16(af[mi], bf[nj], acc[mi][nj], 0, 0, 0);
  }

  // ---------- epilogue ----------
  const int r0 = lg * 4;
  const int bc = n0 + wc * 64;
  #pragma unroll
  for (int mi = 0; mi < 4; ++mi) {
    #pragma unroll
    for (int r = 0; r < 4; ++r) {
      const size_t grow = (size_t)(m0 + wr * 64 + mi * 16 + r0 + r);
      if (OUTMODE == 0) {
        #pragma unroll
        for (int nj = 0; nj < 4; ++nj) {
          const size_t gi = grow * N + (bc + nj * 16 + l15);
          float v = acc[mi][nj][r];
          if (resid) v += resid[gi];
          ((float*)Cout)[gi] = v;
        }
      } else if (OUTMODE == 2) {
        #pragma unroll
        for (int p = 0; p < 2; ++p) {
          float gv = acc[mi][2 * p][r], uv = acc[mi][2 * p + 1][r];
          float res = gv / (1.f + __expf(-gv)) * uv;
          ((unsigned short*)Cout)[grow * (size_t)(N >> 1) + (bc >> 1) + p * 16 + l15] = f2bf(res);
        }
      } else {  // OUTMODE 4: q-rope / k-rope / plain
        bool doR = false; int pos = 0;
        if (bc < 1024)      { doR = true; pos = (int)grow & 7; }
        else if (bc < 1536) { doR = true; pos = 2 * ((int)grow & 7); }
        unsigned short* o16 = (unsigned short*)Cout;
        if (doR) {
          #pragma unroll
          for (int nj = 0; nj < 2; ++nj) {
            float a = acc[mi][nj][r], b = acc[mi][nj + 2][r];
            float c = ct[pos * 32 + nj * 16 + l15];
            float s = st[pos * 32 + nj * 16 + l15];
            o16[grow * N + bc + nj * 16 + l15]       = f2bf(a * c - b * s);
            o16[grow * N + bc + (nj + 2) * 16 + l15] = f2bf(b * c + a * s);
          }
        } else {
          #pragma unroll
          for (int nj = 0; nj < 4; ++nj)
            o16[grow * N + bc + nj * 16 + l15] = f2bf(acc[mi][nj][r]);
        }
      }
    }
  }
}

// ---------- EKV GEMM with fused f32->bf16 A conversion (m97 structure) ----------
// A is fp32 (edge_hidden_states read directly; kills the 402 MB cvt pass).
// A reg-staged (T14 split: issue next tile's f32 loads in compute region;
// cvt + swizzled ds_write_b128 after the top barrier). B via gload_lds.
// Output: bf16 + k-rope on cols [0,512), pos = 2*(row&7)+1 (OUTMODE 3).
__global__ __launch_bounds__(256) void gemm97f(
    const float* __restrict__ Af, const unsigned short* __restrict__ B,
    unsigned short* __restrict__ Cout,
    const float* __restrict__ ct, const float* __restrict__ st,
    int M, int N, int K) {
  __shared__ unsigned short As[4096];
  __shared__ unsigned short Bs[4096];
  const int tid = threadIdx.x;
  const int lane = tid & 63, wid = tid >> 6;
  const int gx = gridDim.x;
  int id = blockIdx.y * gx + blockIdx.x;
  {
    const int nwg = gx * gridDim.y;
    const int cpx = nwg >> 3;
    id = (id & 7) * cpx + (id >> 3);
  }
  const int m0 = (id / gx) * 128, n0 = (id % gx) * 128;
  const int wr = wid >> 1, wc = wid & 1;
  const int l15 = lane & 15, lg = lane >> 4;
  const int NT = K >> 5;

  const int sr = tid >> 2, sc = tid & 3;
  const int cx = sc ^ ((sr >> 1) & 3);           // LDS write chunk (swizzled)
  const float* arow0 = Af + (size_t)(m0 + sr) * K + sc * 8;       // plain src
  const float* arow1 = arow0 + (size_t)64 * K;
  unsigned short* dw0 = As + sr * 32 + cx * 8;
  unsigned short* dw1 = dw0 + 2048;
  const unsigned short* Bsrc = B + (size_t)(n0 + sr) * K + cx * 8; // pre-XOR'd
  const size_t rK64 = (size_t)64 * K;
  const int rck = (lg ^ ((l15 >> 1) & 3)) * 8;

  f32x4 a00, a01, a10, a11;                      // staged f32 for current tile
  { const float* p = arow0; a00 = *(const f32x4*)p; a01 = *(const f32x4*)(p + 4);
    const float* q = arow1; a10 = *(const f32x4*)q; a11 = *(const f32x4*)(q + 4); }

  f32x4 acc[4][4] = {};
  for (int t = 0; t < NT; ++t) {
    __syncthreads();                    // prev reads done; also drains a-loads
    ushort8 w0, w1;
    #pragma unroll
    for (int z = 0; z < 4; ++z) {
      w0[z] = f2bf(a00[z]); w0[z + 4] = f2bf(a01[z]);
      w1[z] = f2bf(a10[z]); w1[z + 4] = f2bf(a11[z]);
    }
    *(ushort8*)dw0 = w0;
    *(ushort8*)dw1 = w1;
    const size_t k0 = (size_t)t * 32;
    gload_lds16(Bsrc + k0,        Bs + wid * 512);
    gload_lds16(Bsrc + rK64 + k0, Bs + 2048 + wid * 512);
    __syncthreads();                    // ds_writes + B gloads visible
    if (t + 1 < NT) {                   // issue next A tile under compute
      const float* p = arow0 + (size_t)(t + 1) * 32;
      const float* q = arow1 + (size_t)(t + 1) * 32;
      a00 = *(const f32x4*)p; a01 = *(const f32x4*)(p + 4);
      a10 = *(const f32x4*)q; a11 = *(const f32x4*)(q + 4);
    }
    bf16x8 af[4], bf[4];
    #pragma unroll
    for (int mi = 0; mi < 4; ++mi)
      af[mi] = *(const bf16x8*)&As[(wr * 64 + mi * 16 + l15) * 32 + rck];
    #pragma unroll
    for (int nj = 0; nj < 4; ++nj)
      bf[nj] = *(const bf16x8*)&Bs[(wc * 64 + nj * 16 + l15) * 32 + rck];
    #pragma unroll
    for (int mi = 0; mi < 4; ++mi)
      #pragma unroll
      for (int nj = 0; nj < 4; ++nj)
        acc[mi][nj] = __builtin_amdgcn_mfma_f32_16x16x32_bf16(af[mi], bf[nj], acc[mi][nj], 0, 0, 0);
  }

  // epilogue: bf16 + k-rope cols [0,512), pos odd
  const int r0 = lg * 4;
  const int bc = n0 + wc * 64;
  #pragma unroll
  for (int mi = 0; mi < 4; ++mi) {
    #pragma unroll
    for (int r = 0; r < 4; ++r) {
      const size_t grow = (size_t)(m0 + wr * 64 + mi * 16 + r0 + r);
      if (bc < 512) {
        const int pos = 2 * ((int)grow & 7) + 1;
        #pragma unroll
        for (int nj = 0; nj < 2; ++nj) {
          float a = acc[mi][nj][r], b = acc[mi][nj + 2][r];
          float c = ct[pos * 32 + nj * 16 + l15];
          float s = st[pos * 32 + nj * 16 + l15];
          Cout[grow * N + bc + nj * 16 + l15]       = f2bf(a * c - b * s);
          Cout[grow * N + bc + (nj + 2) * 16 + l15] = f2bf(b * c + a * s);
        }
      } else {
        #pragma unroll
        for (int nj = 0; nj < 4; ++nj)
          Cout[grow * N + bc + nj * 16 + l15] = f2bf(acc[mi][nj][r]);
      }
    }
  }
}

// ---------- CSR build ----------
__global__ void csr_count_kernel(const int* __restrict__ dst, int* __restrict__ cnt) {
  int e = blockIdx.x * 256 + threadIdx.x;
  if (e < kE) atomicAdd(&cnt[dst[e]], 1);
}
__global__ __launch_bounds__(1024) void csr_scan_kernel(
    const int* __restrict__ cnt, int* __restrict__ start) {
  __shared__ int tmp[1024];
  int t = threadIdx.x;
  tmp[t] = cnt[t];
  __syncthreads();
  for (int off = 1; off < 1024; off <<= 1) {
    int add = (t >= off) ? tmp[t - off] : 0;
    __syncthreads();
    tmp[t] += add;
    __syncthreads();
  }
  start[t + 1] = tmp[t];
  if (t == 0) start[0] = 0;
}
__global__ void csr_scatter_kernel(const int* __restrict__ dst, const int* __restrict__ start,
                                   int* __restrict__ cursor, int* __restrict__ elist) {
  int e = blockIdx.x * 256 + threadIdx.x;
  if (e < kE) {
    int d = dst[e];
    int pos = atomicAdd(&cursor[d], 1);
    elist[start[d] + pos] = e;
  }
}

// ---------- MFMA graph attention: one wave per (node, kv-head) ----------
// qkv rows (8192) = [q 1024 | k 512 | v 512]; ekv rows (65536) = [ek 512 | ev 512].
__global__ __launch_bounds__(256) void attn_mfma_kernel(
    const unsigned short* __restrict__ qkv,  // roped
    const unsigned short* __restrict__ ekv,  // ek roped
    const int* __restrict__ srcIdx, const int* __restrict__ elist,
    const int* __restrict__ start,
    unsigned short* __restrict__ aggb) {
  const int n = blockIdx.x >> 1;
  const int g = (blockIdx.x & 1) * 4 + (threadIdx.x >> 6);
  const int lane = threadIdx.x & 63;
  const int l15 = lane & 15, lg = lane >> 4;

  const int h = g * 2 + (l15 >> 3), q = l15 & 7;
  const unsigned short* qrow = qkv + ((size_t)n * 8 + q) * 2048 + h * 64 + lg * 8;
  const bf16x8 qf0 = *(const bf16x8*)qrow;
  const bf16x8 qf1 = *(const bf16x8*)(qrow + 32);

  float m = -3.4e38f, sh = 0.f;
  f32x4 oacc[4];
  #pragma unroll
  for (int t = 0; t < 4; ++t) oacc[t] = (f32x4){0.f, 0.f, 0.f, 0.f};

  const int kparity = l15 & 1;
  const int t_ = l15 >> 1;
  const int lgh = lg & 1;
  const int eS = lg >> 1;

  const int s0 = start[n], s1 = start[n + 1];
  for (int jj = s0; jj < s1; jj += 2) {
    const int e0 = elist[jj];
    const bool has1 = (jj + 1 < s1);
    const int e1 = has1 ? elist[jj + 1] : e0;
    const int sn0 = srcIdx[e0], sn1 = srcIdx[e1];

    const unsigned short* kr0 = kparity
        ? ekv + ((size_t)e0 * 8 + t_) * 1024 + g * 64 + lg * 8
        : qkv + ((size_t)sn0 * 8 + t_) * 2048 + 1024 + g * 64 + lg * 8;
    const unsigned short* kr1 = kparity
        ? ekv + ((size_t)e1 * 8 + t_) * 1024 + g * 64 + lg * 8
        : qkv + ((size_t)sn1 * 8 + t_) * 2048 + 1024 + g * 64 + lg * 8;
    bf16x8 ka0 = *(const bf16x8*)kr0, ka1 = *(const bf16x8*)(kr0 + 32);
    bf16x8 kc0 = *(const bf16x8*)kr1, kc1 = *(const bf16x8*)(kr1 + 32);

    const int evsel = eS ? e1 : e0;
    const int snsel = eS ? sn1 : sn0;
    const unsigned short* vn = qkv + ((size_t)snsel * 8 + lgh * 4) * 2048 + 1536 + g * 64;
    const unsigned short* ve = ekv + ((size_t)evsel * 8 + lgh * 4) * 1024 + 512 + g * 64;

    f32x4 z = (f32x4){0.f, 0.f, 0.f, 0.f};
    f32x4 sa = __builtin_amdgcn_mfma_f32_16x16x32_bf16(ka0, qf0, z, 0, 0, 0);
    sa       = __builtin_amdgcn_mfma_f32_16x16x32_bf16(ka1, qf1, sa, 0, 0, 0);
    f32x4 sb = __builtin_amdgcn_mfma_f32_16x16x32_bf16(kc0, qf0, z, 0, 0, 0);
    sb       = __builtin_amdgcn_mfma_f32_16x16x32_bf16(kc1, qf1, sb, 0, 0, 0);

    float l0[4], l1[4];
    float lmax = -3.4e38f;
    #pragma unroll
    for (int r = 0; r < 4; ++r) {
      l0[r] = sa[r] * 0.125f;
      l1[r] = has1 ? sb[r] * 0.125f : -3.4e38f;
      lmax = fmaxf(lmax, fmaxf(l0[r], l1[r]));
    }
    lmax = fmaxf(lmax, __shfl_xor(lmax, 16));
    lmax = fmaxf(lmax, __shfl_xor(lmax, 32));
    const float mnew = fmaxf(m, lmax);
    const float scale = __expf(m - mnew);
    float p0[4], p1[4], ps = 0.f;
    #pragma unroll
    for (int r = 0; r < 4; ++r) {
      p0[r] = __expf(l0[r] - mnew);
      p1[r] = __expf(l1[r] - mnew);
      ps += p0[r] + p1[r];
    }
    ps += __shfl_xor(ps, 16);
    ps += __shfl_xor(ps, 32);
    sh = sh * scale + ps;
    m = mnew;

    #pragma unroll
    for (int r = 0; r < 4; ++r) {
      float sr = __shfl(scale, lg * 4 + r);
      #pragma unroll
      for (int t = 0; t < 4; ++t) oacc[t][r] *= sr;
    }

    unsigned w00 = pkbf(p0[0], p0[1]), w01 = pkbf(p0[2], p0[3]);
    unsigned w10 = pkbf(p1[0], p1[1]), w11 = pkbf(p1[2], p1[3]);
    const int L1 = l15 + 32 * lgh, L2 = L1 + 16;
    unsigned a0 = __shfl(w00, L1), a1 = __shfl(w01, L1);
    unsigned a2 = __shfl(w00, L2), a3 = __shfl(w01, L2);
    unsigned b0 = __shfl(w10, L1), b1 = __shfl(w11, L1);
    unsigned b2 = __shfl(w10, L2), b3 = __shfl(w11, L2);
    uint4 wv;
    wv.x = eS ? b0 : a0; wv.y = eS ? b1 : a1;
    wv.z = eS ? b2 : a2; wv.w = eS ? b3 : a3;
    const bf16x8 pf = __builtin_bit_cast(bf16x8, wv);

    #pragma unroll
    for (int t = 0; t < 4; ++t) {
      const int col = t * 16 + l15;
      ushort8 vr;
      #pragma unroll
      for (int j = 0; j < 8; ++j)
        vr[j] = (j & 1) ? ve[(j >> 1) * 1024 + col] : vn[(j >> 1) * 2048 + col];
      const bf16x8 vf = __builtin_bit_cast(bf16x8, vr);
      oacc[t] = __builtin_amdgcn_mfma_f32_16x16x32_bf16(pf, vf, oacc[t], 0, 0, 0);
    }
  }

  #pragma unroll
  for (int r = 0; r < 4; ++r) {
    const float sr = __shfl(sh, lg * 4 + r);
    const float inv = 1.f / (sr + 1e-16f);
    const int hq = lg * 4 + r;
    const int hh = g * 2 + (hq >> 3), qq = hq & 7;
    unsigned short* op = aggb + ((size_t)n * 8 + qq) * 1024 + hh * 64 + l15;
    #pragma unroll
    for (int t = 0; t < 4; ++t) op[t * 16] = f2bf(oacc[t][r] * inv);
  }
}

extern "C" void kernel_launch(void* const* d_in, const int* in_sizes, int n_in,
                              void* d_out, int out_size, void* d_ws, size_t ws_size,
                              hipStream_t stream) {
  const float* hidden = (const float*)d_in[0];
  const int*   eidx   = (const int*)d_in[1];
  const float* ehid   = (const float*)d_in[2];
  const float* Wq     = (const float*)d_in[3];
  const float* Wk     = (const float*)d_in[4];
  const float* Wv     = (const float*)d_in[5];
  const float* Wo     = (const float*)d_in[6];
  const float* Wgate  = (const float*)d_in[7];
  const float* Wup    = (const float*)d_in[8];
  const float* Wdown  = (const float*)d_in[9];
  const float* ln1    = (const float*)d_in[10];
  const float* ln2    = (const float*)d_in[11];
  const int* srcIdx = eidx;
  const int* dstIdx = eidx + kE;

  char* wsb = (char*)d_ws;
  size_t off = 0;
  auto alloc = [&](size_t bytes) { char* p = wsb + off; off += (bytes + 255) & ~(size_t)255; return p; };
  unsigned short* ekv16  = (unsigned short*)alloc(134217728);  // [65536][1024] ek|ev; reused as gm16 [8192][4096]
  unsigned short* qkv16  = (unsigned short*)alloc(33554432);   // [8192][2048] q|k|v
  unsigned short* x16    = (unsigned short*)alloc(16777216);   // [8192][1024]; reused as h216
  unsigned short* agg16  = (unsigned short*)alloc(16777216);   // [8192][1024]
  float*          hbuf   = (float*)alloc(33554432);            // [8192][1024] f32
  unsigned short* wqkv16 = (unsigned short*)alloc(4194304);    // [2048][1024] = Wq|Wk|Wv
  unsigned short* wo16   = (unsigned short*)alloc(2097152);    // [1024][1024]
  unsigned short* wgu16  = (unsigned short*)alloc(16777216);   // [8192][1024] interleaved gate/up
  unsigned short* wd16   = (unsigned short*)alloc(8388608);    // [1024][4096]
  int* cnt    = (int*)alloc(4096);
  int* cursor = (int*)alloc(4096);   // adjacent to cnt -> one memset
  int* startb = (int*)alloc(4352);   // 1025 ints
  int* elist  = (int*)alloc(32768);
  float* ct   = (float*)alloc(2048);
  float* st   = (float*)alloc(2048);
  unsigned short* gm16 = ekv16;   // silu output (ekv dead after attention)
  unsigned short* h216 = x16;     // rmsnorm2 out (x16 dead after QKV GEMM)
  float* outp = (float*)d_out;

  hipMemsetAsync(cnt, 0, 8192, stream);     // cnt + cursor
  rope_tables_kernel<<<1, 512, 0, stream>>>(ct, st);

  // weight conversions (no edge-matrix cvt: fused into the EKV GEMM)
  cvt_kernel<<<512,   256, 0, stream>>>(Wq,    wqkv16,                 131072);
  cvt_kernel<<<256,   256, 0, stream>>>(Wk,    wqkv16 + 1024 * 1024,   65536);
  cvt_kernel<<<256,   256, 0, stream>>>(Wv,    wqkv16 + 1536 * 1024,   65536);
  cvt_kernel<<<512,   256, 0, stream>>>(Wo,    wo16,                  131072);
  cvt_gu_kernel<<<4096, 256, 0, stream>>>(Wgate, Wup, wgu16);
  cvt_kernel<<<2048,  256, 0, stream>>>(Wdown, wd16,                  524288);

  // CSR build
  csr_count_kernel<<<32, 256, 0, stream>>>(dstIdx, cnt);
  csr_scan_kernel<<<1, 1024, 0, stream>>>(cnt, startb);
  csr_scatter_kernel<<<32, 256, 0, stream>>>(dstIdx, startb, cursor, elist);

  // x = rmsnorm(hidden, ln1) -> bf16
  rmsnorm_bf16_kernel<<<kN * kQL, 256, 0, stream>>>(hidden, ln1, x16);

  // fused projections (rope fused in epilogues; EKV converts f32 A on the fly)
  gemm97<4><<<dim3(16, 64), 256, 0, stream>>>(x16, wqkv16, nullptr, qkv16, ct, st, 8192, 2048, 1024);
  gemm97f<<<dim3(8, 512), 256, 0, stream>>>(ehid, wqkv16 + 1024 * 1024, ekv16, ct, st, 65536, 1024, 1024);

  // fused MFMA graph attention
  attn_mfma_kernel<<<2048, 256, 0, stream>>>(qkv16, ekv16, srcIdx, elist, startb, agg16);

  // h = hidden + agg @ Wo^T
  gemm97<0><<<dim3(8, 64), 256, 0, stream>>>(agg16, wo16, hidden, hbuf, ct, st, 8192, 1024, 1024);

  // MLP (silu fused in GateUp epilogue via interleaved weights)
  rmsnorm_bf16_kernel<<<kN * kQL, 256, 0, stream>>>(hbuf, ln2, h216);
  gemm97<2><<<dim3(64, 64), 256, 0, stream>>>(h216, wgu16, nullptr, gm16, ct, st, 8192, 8192, 1024);
  gemm97<0><<<dim3(8, 64), 256, 0, stream>>>(gm16, wd16, hbuf, outp, ct, st, 8192, 1024, 4096);
}

// Round 10
// 749.486 us; speedup vs baseline: 1.0890x; 1.0890x over previous
//
#include <hip/hip_runtime.h>
#include <cstddef>
#include <cstdint>

constexpr int kN    = 1024;
constexpr int kE    = 8192;
constexpr int kQL   = 8;
constexpr int kHID  = 1024;

typedef __bf16 bf16x8 __attribute__((ext_vector_type(8)));
typedef float  f32x4  __attribute__((ext_vector_type(4)));
typedef unsigned short ushort8 __attribute__((ext_vector_type(8)));

__device__ __forceinline__ unsigned short f2bf(float f) {
  unsigned u = __float_as_uint(f);
  unsigned r = (u + 0x7FFFu + ((u >> 16) & 1u)) >> 16;
  return (unsigned short)r;
}
__device__ __forceinline__ float bf2f(unsigned short u) {
  return __uint_as_float((unsigned)u << 16);
}
__device__ __forceinline__ unsigned pkbf(float a, float b) {
  return (unsigned)f2bf(a) | ((unsigned)f2bf(b) << 16);
}
__device__ __forceinline__ void gload_lds16(const void* g, void* l) {
  __builtin_amdgcn_global_load_lds(
      (const __attribute__((address_space(1))) void*)g,
      (__attribute__((address_space(3))) void*)l, 16, 0, 0);
}

// ---------- RoPE tables: ct/st[p][j], p<16, j<32 ----------
__global__ void rope_tables_kernel(float* __restrict__ ct, float* __restrict__ st) {
  int i = threadIdx.x;              // 512 threads
  int p = i >> 5, j = i & 31;
  float inv = expf(-((float)(2 * j) / 64.0f) * logf(10000.0f));
  float ang = (float)p * inv;
  ct[i] = cosf(ang);
  st[i] = sinf(ang);
}

// ---------- fp32 -> bf16 convert (8 elems/thread) ----------
__global__ __launch_bounds__(256) void cvt_kernel(
    const float* __restrict__ in, unsigned short* __restrict__ out, int n8) {
  int i = blockIdx.x * 256 + threadIdx.x;
  if (i >= n8) return;
  const float4* p = (const float4*)(in + (size_t)i * 8);
  float4 a = p[0], b = p[1];
  uint4 o;
  o.x = f2bf(a.x) | ((unsigned)f2bf(a.y) << 16);
  o.y = f2bf(a.z) | ((unsigned)f2bf(a.w) << 16);
  o.z = f2bf(b.x) | ((unsigned)f2bf(b.y) << 16);
  o.w = f2bf(b.z) | ((unsigned)f2bf(b.w) << 16);
  *(uint4*)(out + (size_t)i * 8) = o;
}

// ---------- gate/up weights -> 16-col interleaved fused layout ----------
__global__ __launch_bounds__(256) void cvt_gu_kernel(
    const float* __restrict__ Wg, const float* __restrict__ Wu,
    unsigned short* __restrict__ out) {
  int i = blockIdx.x * 256 + threadIdx.x;   // 8192*128
  int n = i >> 7, ck = (i & 127) * 8;
  int isUp = (n >> 4) & 1;
  int srow = (n >> 6) * 32 + ((n >> 5) & 1) * 16 + (n & 15);
  const float* src = (isUp ? Wu : Wg) + (size_t)srow * 1024 + ck;
  const float4* p = (const float4*)src;
  float4 a = p[0], b = p[1];
  uint4 o;
  o.x = f2bf(a.x) | ((unsigned)f2bf(a.y) << 16);
  o.y = f2bf(a.z) | ((unsigned)f2bf(a.w) << 16);
  o.z = f2bf(b.x) | ((unsigned)f2bf(b.y) << 16);
  o.w = f2bf(b.z) | ((unsigned)f2bf(b.w) << 16);
  *(uint4*)(out + (size_t)n * 1024 + ck) = o;
}

// ---------- RMSNorm: fp32 in -> bf16 out, one block per row ----------
__global__ __launch_bounds__(256) void rmsnorm_bf16_kernel(
    const float* __restrict__ in, const float* __restrict__ w,
    unsigned short* __restrict__ out) {
  __shared__ float red[4];
  int row = blockIdx.x, tid = threadIdx.x;
  const float* p = in + (size_t)row * kHID + tid * 4;
  float4 v = *(const float4*)p;
  float ss = v.x*v.x + v.y*v.y + v.z*v.z + v.w*v.w;
  #pragma unroll
  for (int off = 32; off > 0; off >>= 1) ss += __shfl_down(ss, off);
  int lane = tid & 63, wv = tid >> 6;
  if (lane == 0) red[wv] = ss;
  __syncthreads();
  float tot = red[0] + red[1] + red[2] + red[3];
  float rn = rsqrtf(tot * (1.0f / (float)kHID) + 1e-6f);
  float4 w4 = *(const float4*)(w + tid * 4);
  uint2 o;
  o.x = f2bf(v.x*rn*w4.x) | ((unsigned)f2bf(v.y*rn*w4.y) << 16);
  o.y = f2bf(v.z*rn*w4.z) | ((unsigned)f2bf(v.w*rn*w4.w) << 16);
  *(uint2*)(out + (size_t)row * kHID + tid * 4) = o;
}

// ---------- TMx128 bf16 MFMA GEMM, 4 waves, HK-density wave tiles ----------
// C[M,N] = A[M,K]*B[N,K]^T. 256 thr = 4 waves (2M x 2N). Wave tile =
// (TM/2)x64: TM=256 -> 128x64/wave (32 MFMA per 12 ds_read, 2.67 density),
// TM=128 -> 64x64 (2.0). BK=32, 3-buffer LDS (72/48 KiB -> 2/3 blocks/CU).
// r8-proven loop: single barrier/K-tile, counted vmcnt(LPS) (prefetch dist 2,
// never drains mid-loop), chunk-XOR swizzle f(row)=(row>>1)&3 (0-conflict,
// R8-verified; invariant under +64-row offsets) on stage-source + read side.
// OUTMODE: 0=f32(+resid)  2=silu(gate)*up pairs->bf16 (N_out=N/2)
//          4=bf16 + q-rope cols [0,1024), k-rope [1024,1536) pos even
//          3=bf16 + k-rope cols [0,512) pos odd
template<int OUTMODE, int TM>
__global__ __launch_bounds__(256, (TM == 256) ? 2 : 3) void gemmw(
    const unsigned short* __restrict__ A, const unsigned short* __restrict__ B,
    const float* __restrict__ resid, void* __restrict__ Cout,
    const float* __restrict__ ct, const float* __restrict__ st,
    int M, int N, int K) {
  constexpr int ABUFE = TM * 32;             // elems per A buffer
  constexpr int BBUFE = 128 * 32;
  constexpr int WRS   = TM / 2;              // wave row span: 128 or 64
  constexpr int MI    = WRS / 16;            // 8 or 4
  constexpr int AR    = TM / 64;             // A stage rounds: 4 or 2
  constexpr int LPS   = AR + 2;              // gloads per stage per wave
  __shared__ unsigned short As[3 * ABUFE];
  __shared__ unsigned short Bs[3 * BBUFE];
  const int tid = threadIdx.x;
  const int lane = tid & 63, wid = tid >> 6;
  const int gx = gridDim.x;
  int id = blockIdx.y * gx + blockIdx.x;
  {
    const int nwg = gx * gridDim.y;          // all grids here are %8 == 0
    const int cpx = nwg >> 3;
    id = (id & 7) * cpx + (id >> 3);         // XCD-contiguous remap
  }
  const int m0 = (id / gx) * TM, n0 = (id % gx) * 128;
  const int wr = wid >> 1, wc = wid & 1;
  const int l15 = lane & 15, lg = lane >> 4;
  const int NT = K >> 5;

  // staging: thread t covers rows (t>>2) + r*64, chunk t&3; source chunk
  // pre-XOR'd so LDS[row][c] = global[row][c ^ ((row>>1)&3)].
  // ((row+64k)>>1)&3 == (row>>1)&3, so one pointer serves all rounds.
  const int sr = tid >> 2, sc = tid & 3;
  const unsigned short* Asrc = A + (size_t)(m0 + sr) * K + (sc ^ ((sr >> 1) & 3)) * 8;
  const unsigned short* Bsrc = B + (size_t)(n0 + sr) * K + (sc ^ ((sr >> 1) & 3)) * 8;
  const size_t rK64 = (size_t)64 * K;

#define STAGE(t_, b_) do {                                                   \
    const size_t _k0 = (size_t)(t_) * 32;                                    \
    _Pragma("unroll")                                                        \
    for (int rr = 0; rr < AR; ++rr)                                          \
      gload_lds16(Asrc + rr * rK64 + _k0,                                    \
                  As + (b_) * ABUFE + (wid * 16 + rr * 64) * 32);            \
    _Pragma("unroll")                                                        \
    for (int rr = 0; rr < 2; ++rr)                                           \
      gload_lds16(Bsrc + rr * rK64 + _k0,                                    \
                  Bs + (b_) * BBUFE + (wid * 16 + rr * 64) * 32);            \
  } while (0)

  f32x4 acc[MI][4] = {};
  STAGE(0, 0); STAGE(1, 1);

  const int rck = (lg ^ ((l15 >> 1) & 3)) * 8;   // read-side swizzle chunk
  int cur = 0, nx2 = 2;
  for (int t = 0; t < NT; ++t) {
    __builtin_amdgcn_sched_barrier(0);
    if (t + 1 < NT) asm volatile("s_waitcnt vmcnt(%0)" :: "i"(LPS) : "memory");
    else            asm volatile("s_waitcnt vmcnt(0)" ::: "memory");
    __builtin_amdgcn_s_barrier();
    __builtin_amdgcn_sched_barrier(0);
    if (t + 2 < NT) STAGE(t + 2, nx2);

    const unsigned short* Ab = As + cur * ABUFE + (wr * WRS + l15) * 32 + rck;
    const unsigned short* Bb = Bs + cur * BBUFE + (wc * 64 + l15) * 32 + rck;
    bf16x8 af[MI], bf[4];
    #pragma unroll
    for (int mi = 0; mi < MI; ++mi) af[mi] = *(const bf16x8*)(Ab + mi * 512);
    #pragma unroll
    for (int nj = 0; nj < 4; ++nj) bf[nj] = *(const bf16x8*)(Bb + nj * 512);
    __builtin_amdgcn_s_setprio(1);
    #pragma unroll
    for (int mi = 0; mi < MI; ++mi)
      #pragma unroll
      for (int nj = 0; nj < 4; ++nj)
        acc[mi][nj] = __builtin_amdgcn_mfma_f32_16x16x32_bf16(af[mi], bf[nj], acc[mi][nj], 0, 0, 0);
    __builtin_amdgcn_s_setprio(0);
    cur = (cur == 2) ? 0 : cur + 1;
    nx2 = (nx2 == 2) ? 0 : nx2 + 1;
  }
#undef STAGE

  // ---------- epilogue ----------
  const int r0 = lg * 4;
  const int bc = n0 + wc * 64;
  #pragma unroll
  for (int mi = 0; mi < MI; ++mi) {
    #pragma unroll
    for (int r = 0; r < 4; ++r) {
      const size_t grow = (size_t)(m0 + wr * WRS + mi * 16 + r0 + r);
      if (OUTMODE == 0) {
        #pragma unroll
        for (int nj = 0; nj < 4; ++nj) {
          const size_t gi = grow * N + (bc + nj * 16 + l15);
          float v = acc[mi][nj][r];
          if (resid) v += resid[gi];
          ((float*)Cout)[gi] = v;
        }
      } else if (OUTMODE == 2) {
        #pragma unroll
        for (int p = 0; p < 2; ++p) {
          float gv = acc[mi][2 * p][r], uv = acc[mi][2 * p + 1][r];
          float res = gv / (1.f + __expf(-gv)) * uv;
          ((unsigned short*)Cout)[grow * (size_t)(N >> 1) + (bc >> 1) + p * 16 + l15] = f2bf(res);
        }
      } else {
        bool doR = false; int pos = 0;
        if (OUTMODE == 3) { doR = bc < 512; pos = 2 * ((int)grow & 7) + 1; }
        if (OUTMODE == 4) {
          if (bc < 1024)      { doR = true; pos = (int)grow & 7; }
          else if (bc < 1536) { doR = true; pos = 2 * ((int)grow & 7); }
        }
        unsigned short* o16 = (unsigned short*)Cout;
        if (doR) {
          #pragma unroll
          for (int nj = 0; nj < 2; ++nj) {
            float a = acc[mi][nj][r], b = acc[mi][nj + 2][r];
            float c = ct[pos * 32 + nj * 16 + l15];
            float s = st[pos * 32 + nj * 16 + l15];
            o16[grow * N + bc + nj * 16 + l15]       = f2bf(a * c - b * s);
            o16[grow * N + bc + (nj + 2) * 16 + l15] = f2bf(b * c + a * s);
          }
        } else {
          #pragma unroll
          for (int nj = 0; nj < 4; ++nj)
            o16[grow * N + bc + nj * 16 + l15] = f2bf(acc[mi][nj][r]);
        }
      }
    }
  }
}

// ---------- CSR build ----------
__global__ void csr_count_kernel(const int* __restrict__ dst, int* __restrict__ cnt) {
  int e = blockIdx.x * 256 + threadIdx.x;
  if (e < kE) atomicAdd(&cnt[dst[e]], 1);
}
__global__ __launch_bounds__(1024) void csr_scan_kernel(
    const int* __restrict__ cnt, int* __restrict__ start) {
  __shared__ int tmp[1024];
  int t = threadIdx.x;
  tmp[t] = cnt[t];
  __syncthreads();
  for (int off = 1; off < 1024; off <<= 1) {
    int add = (t >= off) ? tmp[t - off] : 0;
    __syncthreads();
    tmp[t] += add;
    __syncthreads();
  }
  start[t + 1] = tmp[t];
  if (t == 0) start[0] = 0;
}
__global__ void csr_scatter_kernel(const int* __restrict__ dst, const int* __restrict__ start,
                                   int* __restrict__ cursor, int* __restrict__ elist) {
  int e = blockIdx.x * 256 + threadIdx.x;
  if (e < kE) {
    int d = dst[e];
    int pos = atomicAdd(&cursor[d], 1);
    elist[start[d] + pos] = e;
  }
}

// ---------- MFMA graph attention: one wave per (node, kv-head) ----------
// qkv rows (8192) = [q 1024 | k 512 | v 512]; ekv rows (65536) = [ek 512 | ev 512].
__global__ __launch_bounds__(256) void attn_mfma_kernel(
    const unsigned short* __restrict__ qkv,  // roped
    const unsigned short* __restrict__ ekv,  // ek roped
    const int* __restrict__ srcIdx, const int* __restrict__ elist,
    const int* __restrict__ start,
    unsigned short* __restrict__ aggb) {
  const int n = blockIdx.x >> 1;
  const int g = (blockIdx.x & 1) * 4 + (threadIdx.x >> 6);
  const int lane = threadIdx.x & 63;
  const int l15 = lane & 15, lg = lane >> 4;

  const int h = g * 2 + (l15 >> 3), q = l15 & 7;
  const unsigned short* qrow = qkv + ((size_t)n * 8 + q) * 2048 + h * 64 + lg * 8;
  const bf16x8 qf0 = *(const bf16x8*)qrow;
  const bf16x8 qf1 = *(const bf16x8*)(qrow + 32);

  float m = -3.4e38f, sh = 0.f;
  f32x4 oacc[4];
  #pragma unroll
  for (int t = 0; t < 4; ++t) oacc[t] = (f32x4){0.f, 0.f, 0.f, 0.f};

  const int kparity = l15 & 1;
  const int t_ = l15 >> 1;
  const int lgh = lg & 1;
  const int eS = lg >> 1;

  const int s0 = start[n], s1 = start[n + 1];
  for (int jj = s0; jj < s1; jj += 2) {
    const int e0 = elist[jj];
    const bool has1 = (jj + 1 < s1);
    const int e1 = has1 ? elist[jj + 1] : e0;
    const int sn0 = srcIdx[e0], sn1 = srcIdx[e1];

    const unsigned short* kr0 = kparity
        ? ekv + ((size_t)e0 * 8 + t_) * 1024 + g * 64 + lg * 8
        : qkv + ((size_t)sn0 * 8 + t_) * 2048 + 1024 + g * 64 + lg * 8;
    const unsigned short* kr1 = kparity
        ? ekv + ((size_t)e1 * 8 + t_) * 1024 + g * 64 + lg * 8
        : qkv + ((size_t)sn1 * 8 + t_) * 2048 + 1024 + g * 64 + lg * 8;
    bf16x8 ka0 = *(const bf16x8*)kr0, ka1 = *(const bf16x8*)(kr0 + 32);
    bf16x8 kc0 = *(const bf16x8*)kr1, kc1 = *(const bf16x8*)(kr1 + 32);

    const int evsel = eS ? e1 : e0;
    const int snsel = eS ? sn1 : sn0;
    const unsigned short* vn = qkv + ((size_t)snsel * 8 + lgh * 4) * 2048 + 1536 + g * 64;
    const unsigned short* ve = ekv + ((size_t)evsel * 8 + lgh * 4) * 1024 + 512 + g * 64;

    f32x4 z = (f32x4){0.f, 0.f, 0.f, 0.f};
    f32x4 sa = __builtin_amdgcn_mfma_f32_16x16x32_bf16(ka0, qf0, z, 0, 0, 0);
    sa       = __builtin_amdgcn_mfma_f32_16x16x32_bf16(ka1, qf1, sa, 0, 0, 0);
    f32x4 sb = __builtin_amdgcn_mfma_f32_16x16x32_bf16(kc0, qf0, z, 0, 0, 0);
    sb       = __builtin_amdgcn_mfma_f32_16x16x32_bf16(kc1, qf1, sb, 0, 0, 0);

    float l0[4], l1[4];
    float lmax = -3.4e38f;
    #pragma unroll
    for (int r = 0; r < 4; ++r) {
      l0[r] = sa[r] * 0.125f;
      l1[r] = has1 ? sb[r] * 0.125f : -3.4e38f;
      lmax = fmaxf(lmax, fmaxf(l0[r], l1[r]));
    }
    lmax = fmaxf(lmax, __shfl_xor(lmax, 16));
    lmax = fmaxf(lmax, __shfl_xor(lmax, 32));
    const float mnew = fmaxf(m, lmax);
    const float scale = __expf(m - mnew);
    float p0[4], p1[4], ps = 0.f;
    #pragma unroll
    for (int r = 0; r < 4; ++r) {
      p0[r] = __expf(l0[r] - mnew);
      p1[r] = __expf(l1[r] - mnew);
      ps += p0[r] + p1[r];
    }
    ps += __shfl_xor(ps, 16);
    ps += __shfl_xor(ps, 32);
    sh = sh * scale + ps;
    m = mnew;

    #pragma unroll
    for (int r = 0; r < 4; ++r) {
      float sr = __shfl(scale, lg * 4 + r);
      #pragma unroll
      for (int t = 0; t < 4; ++t) oacc[t][r] *= sr;
    }

    unsigned w00 = pkbf(p0[0], p0[1]), w01 = pkbf(p0[2], p0[3]);
    unsigned w10 = pkbf(p1[0], p1[1]), w11 = pkbf(p1[2], p1[3]);
    const int L1 = l15 + 32 * lgh, L2 = L1 + 16;
    unsigned a0 = __shfl(w00, L1), a1 = __shfl(w01, L1);
    unsigned a2 = __shfl(w00, L2), a3 = __shfl(w01, L2);
    unsigned b0 = __shfl(w10, L1), b1 = __shfl(w11, L1);
    unsigned b2 = __shfl(w10, L2), b3 = __shfl(w11, L2);
    uint4 wv;
    wv.x = eS ? b0 : a0; wv.y = eS ? b1 : a1;
    wv.z = eS ? b2 : a2; wv.w = eS ? b3 : a3;
    const bf16x8 pf = __builtin_bit_cast(bf16x8, wv);

    #pragma unroll
    for (int t = 0; t < 4; ++t) {
      const int col = t * 16 + l15;
      ushort8 vr;
      #pragma unroll
      for (int j = 0; j < 8; ++j)
        vr[j] = (j & 1) ? ve[(j >> 1) * 1024 + col] : vn[(j >> 1) * 2048 + col];
      const bf16x8 vf = __builtin_bit_cast(bf16x8, vr);
      oacc[t] = __builtin_amdgcn_mfma_f32_16x16x32_bf16(pf, vf, oacc[t], 0, 0, 0);
    }
  }

  #pragma unroll
  for (int r = 0; r < 4; ++r) {
    const float sr = __shfl(sh, lg * 4 + r);
    const float inv = 1.f / (sr + 1e-16f);
    const int hq = lg * 4 + r;
    const int hh = g * 2 + (hq >> 3), qq = hq & 7;
    unsigned short* op = aggb + ((size_t)n * 8 + qq) * 1024 + hh * 64 + l15;
    #pragma unroll
    for (int t = 0; t < 4; ++t) op[t * 16] = f2bf(oacc[t][r] * inv);
  }
}

extern "C" void kernel_launch(void* const* d_in, const int* in_sizes, int n_in,
                              void* d_out, int out_size, void* d_ws, size_t ws_size,
                              hipStream_t stream) {
  const float* hidden = (const float*)d_in[0];
  const int*   eidx   = (const int*)d_in[1];
  const float* ehid   = (const float*)d_in[2];
  const float* Wq     = (const float*)d_in[3];
  const float* Wk     = (const float*)d_in[4];
  const float* Wv     = (const float*)d_in[5];
  const float* Wo     = (const float*)d_in[6];
  const float* Wgate  = (const float*)d_in[7];
  const float* Wup    = (const float*)d_in[8];
  const float* Wdown  = (const float*)d_in[9];
  const float* ln1    = (const float*)d_in[10];
  const float* ln2    = (const float*)d_in[11];
  const int* srcIdx = eidx;
  const int* dstIdx = eidx + kE;

  char* wsb = (char*)d_ws;
  size_t off = 0;
  auto alloc = [&](size_t bytes) { char* p = wsb + off; off += (bytes + 255) & ~(size_t)255; return p; };
  unsigned short* eh16   = (unsigned short*)alloc(134217728);  // [65536][1024]
  unsigned short* ekv16  = (unsigned short*)alloc(134217728);  // [65536][1024] ek|ev; reused as gm16 [8192][4096]
  unsigned short* qkv16  = (unsigned short*)alloc(33554432);   // [8192][2048] q|k|v
  unsigned short* x16    = (unsigned short*)alloc(16777216);   // [8192][1024]; reused as h216
  unsigned short* agg16  = (unsigned short*)alloc(16777216);   // [8192][1024]
  float*          hbuf   = (float*)alloc(33554432);            // [8192][1024] f32
  unsigned short* wqkv16 = (unsigned short*)alloc(4194304);    // [2048][1024] = Wq|Wk|Wv
  unsigned short* wo16   = (unsigned short*)alloc(2097152);    // [1024][1024]
  unsigned short* wgu16  = (unsigned short*)alloc(16777216);   // [8192][1024] interleaved gate/up
  unsigned short* wd16   = (unsigned short*)alloc(8388608);    // [1024][4096]
  int* cnt    = (int*)alloc(4096);
  int* cursor = (int*)alloc(4096);   // adjacent to cnt -> one memset
  int* startb = (int*)alloc(4352);   // 1025 ints
  int* elist  = (int*)alloc(32768);
  float* ct   = (float*)alloc(2048);
  float* st   = (float*)alloc(2048);
  unsigned short* gm16 = ekv16;   // silu output (ekv dead after attention)
  unsigned short* h216 = x16;     // rmsnorm2 out (x16 dead after QKV GEMM)
  float* outp = (float*)d_out;

  hipMemsetAsync(cnt, 0, 8192, stream);     // cnt + cursor
  rope_tables_kernel<<<1, 512, 0, stream>>>(ct, st);

  // fp32 -> bf16 conversions (into fused weight layouts)
  cvt_kernel<<<32768, 256, 0, stream>>>(ehid,  eh16, 8388608);
  cvt_kernel<<<512,   256, 0, stream>>>(Wq,    wqkv16,                 131072);
  cvt_kernel<<<256,   256, 0, stream>>>(Wk,    wqkv16 + 1024 * 1024,   65536);
  cvt_kernel<<<256,   256, 0, stream>>>(Wv,    wqkv16 + 1536 * 1024,   65536);
  cvt_kernel<<<512,   256, 0, stream>>>(Wo,    wo16,                  131072);
  cvt_gu_kernel<<<4096, 256, 0, stream>>>(Wgate, Wup, wgu16);
  cvt_kernel<<<2048,  256, 0, stream>>>(Wdown, wd16,                  524288);

  // CSR build
  csr_count_kernel<<<32, 256, 0, stream>>>(dstIdx, cnt);
  csr_scan_kernel<<<1, 1024, 0, stream>>>(cnt, startb);
  csr_scatter_kernel<<<32, 256, 0, stream>>>(dstIdx, startb, cursor, elist);

  // x = rmsnorm(hidden, ln1) -> bf16
  rmsnorm_bf16_kernel<<<kN * kQL, 256, 0, stream>>>(hidden, ln1, x16);

  // fused projections (rope fused in epilogues)
  gemmw<4, 256><<<dim3(16, 32), 256, 0, stream>>>(x16,  wqkv16, nullptr, qkv16, ct, st, 8192, 2048, 1024);
  gemmw<3, 256><<<dim3(8, 256), 256, 0, stream>>>(eh16, wqkv16 + 1024 * 1024, nullptr, ekv16, ct, st, 65536, 1024, 1024);

  // fused MFMA graph attention
  attn_mfma_kernel<<<2048, 256, 0, stream>>>(qkv16, ekv16, srcIdx, elist, startb, agg16);

  // h = hidden + agg @ Wo^T
  gemmw<0, 128><<<dim3(8, 64), 256, 0, stream>>>(agg16, wo16, hidden, hbuf, ct, st, 8192, 1024, 1024);

  // MLP (silu fused in GateUp epilogue via interleaved weights)
  rmsnorm_bf16_kernel<<<kN * kQL, 256, 0, stream>>>(hbuf, ln2, h216);
  gemmw<2, 256><<<dim3(64, 32), 256, 0, stream>>>(h216, wgu16, nullptr, gm16, ct, st, 8192, 8192, 1024);
  gemmw<0, 128><<<dim3(8, 64), 256, 0, stream>>>(gm16, wd16, hbuf, outp, ct, st, 8192, 1024, 4096);
}